// Round 2
// baseline (610.662 us; speedup 1.0000x reference)
//
#include <hip/hip_runtime.h>
#include <hip/hip_cooperative_groups.h>

namespace cg = cooperative_groups;

#define EPS 1e-5f

// B=32, C=256, CC=64, template 14x14, search 64x64, K=7, 32 groups (2ch/group)
// Single cooperative kernel: 256 blocks x 512 threads, 7 grid syncs.

typedef __attribute__((ext_vector_type(8))) short short8;
typedef __attribute__((ext_vector_type(4))) float floatx4;

__device__ __forceinline__ unsigned short f2bf(float x) {
    union { float f; unsigned u; } v; v.f = x;
    unsigned r = v.u + 0x7FFFu + ((v.u >> 16) & 1u);   // RNE
    return (unsigned short)(r >> 16);
}
__device__ __forceinline__ float bf2f(unsigned short h) {
    union { unsigned u; float f; } v; v.u = ((unsigned)h) << 16;
    return v.f;
}
#define BFLO(u) bf2f((unsigned short)((u) & 0xFFFFu))
#define BFHI(u) bf2f((unsigned short)((u) >> 16))

struct Params {
    const float* tmpl; const float* search;
    const float* w_t; const float* gn_t_w; const float* gn_t_b;
    const float* w_s; const float* gn_s_w; const float* gn_s_b;
    const float* w_p1; const float* gn_p_w; const float* gn_p_b;
    const float* w_p2; const float* b_p2;
    float* TG; float* TK;
    float* AS; float* BS; float* AY; float* BY;
    float* P1; float* P2;
    unsigned short* WPK; unsigned short* WSB;
    float* SRAW;
    unsigned short* CORRB; unsigned short* CORRT; unsigned short* YRAW;
    float* out;
};

__global__ __launch_bounds__(512, 2) void fused(Params P)
{
    const int tid = threadIdx.x;
    const int blk = blockIdx.x;
    cg::grid_group grid = cg::this_grid();
    __shared__ __align__(16) char smem[54784];

    // ================= P0: template path (blocks 0-127) + weight packing (128-255) =================
    if (blk < 128) {
        int b = blk >> 2, h = blk & 3;
        float (*Xs)[200] = (float(*)[200])smem;              // 25600 B
        float (*T0)[200] = (float(*)[200])(smem + 25600);    // 12800 B
        float* sums  = (float*)(smem + 38400);
        float* sumsq = (float*)(smem + 38464);
        float* Ac    = (float*)(smem + 38528);
        float* Bb    = (float*)(smem + 38592);
        float acc[16];
        #pragma unroll
        for (int o = 0; o < 16; ++o) acc[o] = 0.f;
        const float* wb = P.w_t + (h * 16) * 256;
        const float* tb = P.tmpl + b * 50176;
        int p = tid;
        for (int chunk = 0; chunk < 8; ++chunk) {
            __syncthreads();
            #pragma unroll
            for (int j = 0; j < 4; ++j) {
                int f4 = tid + (j << 9);
                if (f4 < 1568) {                        // 32 rows x 49 float4
                    int ic = f4 / 49, px4 = (f4 - ic * 49) << 2;
                    float4 v = *(const float4*)(tb + (chunk * 32 + ic) * 196 + px4);
                    *(float4*)&Xs[ic][px4] = v;
                }
            }
            __syncthreads();
            if (p < 196) {
                for (int cc = 0; cc < 32; ++cc) {
                    float xv = Xs[cc][p];
                    #pragma unroll
                    for (int o = 0; o < 16; ++o)
                        acc[o] += xv * wb[o * 256 + chunk * 32 + cc];
                }
            }
        }
        __syncthreads();
        if (p < 196) {
            #pragma unroll
            for (int o = 0; o < 16; ++o) T0[o][p] = acc[o];
        }
        __syncthreads();
        if (tid < 256) {   // parallel per-channel stats: 16 lanes per channel
            int c = tid >> 4, part = tid & 15;
            float s = 0.f, s2 = 0.f;
            for (int qq = part; qq < 196; qq += 16) { float v = T0[c][qq]; s += v; s2 += v * v; }
            #pragma unroll
            for (int off = 1; off < 16; off <<= 1) {
                s += __shfl_xor(s, off, 16); s2 += __shfl_xor(s2, off, 16);
            }
            if (part == 0) { sums[c] = s; sumsq[c] = s2; }
        }
        __syncthreads();
        if (tid < 8) {   // group = channel pair
            float S  = sums[2 * tid] + sums[2 * tid + 1];
            float S2 = sumsq[2 * tid] + sumsq[2 * tid + 1];
            float mean = S * (1.f / 392.f);
            float var  = S2 * (1.f / 392.f) - mean * mean;
            float inv  = rsqrtf(var + EPS);
            for (int e = 0; e < 2; ++e) {
                int c = 2 * tid + e, gc = h * 16 + c;
                float a = P.gn_t_w[gc] * inv;
                Ac[c] = a; Bb[c] = P.gn_t_b[gc] - mean * a;
            }
        }
        __syncthreads();
        if (p < 196) {
            #pragma unroll
            for (int o = 0; o < 16; ++o) {
                float v = Ac[o] * T0[o][p] + Bb[o];
                T0[o][p] = v > 0.f ? v : 0.f;
            }
        }
        __syncthreads();
        if (tid < 256) {
            int c = tid >> 4, part = tid & 15, gc = h * 16 + c;
            float s = 0.f;
            for (int qq = part; qq < 196; qq += 16) s += T0[c][qq];
            #pragma unroll
            for (int off = 1; off < 16; off <<= 1) s += __shfl_xor(s, off, 16);
            if (part == 0) P.TG[b * 64 + gc] = s * (1.f / 196.f);
            for (int t = part; t < 49; t += 16) {
                int ky = t / 7, kx = t - 7 * ky;
                float v = T0[c][(2 * ky) * 14 + 2 * kx]     + T0[c][(2 * ky) * 14 + 2 * kx + 1]
                        + T0[c][(2 * ky + 1) * 14 + 2 * kx] + T0[c][(2 * ky + 1) * 14 + 2 * kx + 1];
                P.TK[(b * 64 + gc) * 49 + t] = v * 0.25f;
            }
        }
    } else {
        // weight packing: 128 blocks x 512 threads = 65536 >= 53248 jobs
        int idx = ((blk - 128) << 9) + tid;
        if (idx < 16384) {
            P.WSB[idx] = f2bf(P.w_s[idx]);
        } else if (idx < 53248) {
            int i = idx - 16384;
            int c = i >> 11, rem = i & 2047, oc = rem >> 5, k = rem & 31;
            int tap = c >> 1, ic = ((c & 1) << 5) + k;
            P.WPK[i] = f2bf(P.w_p1[oc * 576 + ic * 9 + tap]);
        }
    }
    grid.sync();

    // ================= P1: search conv1x1 MFMA + fused GN stat partials (512 jobs, 2 reps) =================
    {
        short* tile = (short*)smem;                          // 32768 B
        float (*Ps)[64]  = (float(*)[64])(smem + 32768);     // 2048 B
        float (*Ps2)[64] = (float(*)[64])(smem + 34816);     // 2048 B
        int wave = tid >> 6, lane = tid & 63, q = lane >> 4, l15 = lane & 15;
        int pxt = tid & 255, hf = tid >> 8;
        for (int rep = 0; rep < 2; ++rep) {
            int job = blk + (rep << 8);
            int b = job >> 4, p0 = (job & 15) << 8;
            floatx4 acc[2][4];
            #pragma unroll
            for (int i = 0; i < 2; ++i)
                #pragma unroll
                for (int mt = 0; mt < 4; ++mt) acc[i][mt] = (floatx4){0.f, 0.f, 0.f, 0.f};
            const float* xb = P.search + ((long)b << 20) + p0 + pxt;
            for (int chunk = 0; chunk < 4; ++chunk) {
                __syncthreads();
                float v[32];
                #pragma unroll
                for (int i = 0; i < 32; ++i)
                    v[i] = xb[(long)((chunk << 6) + (hf << 5) + i) << 12];
                #pragma unroll
                for (int b4 = 0; b4 < 4; ++b4) {
                    int icblk = (hf << 2) + b4;
                    short8 s8;
                    #pragma unroll
                    for (int e = 0; e < 8; ++e) s8[e] = (short)f2bf(v[(b4 << 3) + e]);
                    int sw = icblk ^ (pxt & 7);
                    *(short8*)&tile[(pxt << 6) + (sw << 3)] = s8;
                }
                __syncthreads();
                #pragma unroll
                for (int kq = 0; kq < 2; ++kq) {
                    short8 afr[4], bfr[2];
                    int kbase = (chunk << 6) + (kq << 5) + (q << 3);
                    #pragma unroll
                    for (int mt = 0; mt < 4; ++mt)
                        afr[mt] = *(const short8*)(P.WSB + ((mt << 4) + l15) * 256 + kbase);
                    #pragma unroll
                    for (int i = 0; i < 2; ++i) {
                        int px = (((wave << 1) + i) << 4) + l15;
                        int sw = ((kq << 2) + q) ^ (px & 7);
                        bfr[i] = *(const short8*)&tile[(px << 6) + (sw << 3)];
                    }
                    #pragma unroll
                    for (int i = 0; i < 2; ++i)
                        #pragma unroll
                        for (int mt = 0; mt < 4; ++mt)
                            acc[i][mt] = __builtin_amdgcn_mfma_f32_16x16x32_bf16(afr[mt], bfr[i], acc[i][mt], 0, 0, 0);
                }
            }
            float* ob = P.SRAW + ((long)b << 18) + p0;
            #pragma unroll
            for (int i = 0; i < 2; ++i) {
                int pxb = ((wave << 1) + i) << 4;
                #pragma unroll
                for (int mt = 0; mt < 4; ++mt)
                    #pragma unroll
                    for (int r = 0; r < 4; ++r) {
                        int oc = (mt << 4) + (q << 2) + r;
                        ob[(oc << 12) + pxb + l15] = acc[i][mt][r];
                    }
            }
            #pragma unroll
            for (int mt = 0; mt < 4; ++mt) {
                #pragma unroll
                for (int r = 0; r < 4; ++r) {
                    float s = 0.f, s2 = 0.f;
                    #pragma unroll
                    for (int i = 0; i < 2; ++i) { float v = acc[i][mt][r]; s += v; s2 += v * v; }
                    #pragma unroll
                    for (int off = 1; off < 16; off <<= 1) {
                        s  += __shfl_xor(s, off, 64);
                        s2 += __shfl_xor(s2, off, 64);
                    }
                    if (l15 == 0) {
                        int oc = (mt << 4) + (q << 2) + r;
                        Ps[wave][oc] = s; Ps2[wave][oc] = s2;
                    }
                }
            }
            __syncthreads();
            if (tid < 64) {
                float s = 0.f, s2 = 0.f;
                #pragma unroll
                for (int w = 0; w < 8; ++w) { s += Ps[w][tid]; s2 += Ps2[w][tid]; }
                int idx = (((b << 4) + (job & 15)) << 6) + tid;
                P.P1[idx] = s; P.P2[idx] = s2;
            }
        }
    }
    grid.sync();

    // ================= P2: finalize s-GN coefs =================
    if (blk < 32 && tid < 64) {
        int b = blk, c = tid;
        float s = 0.f, s2 = 0.f;
        for (int t = 0; t < 16; ++t) {
            int idx = (((b << 4) + t) << 6) + c;
            s += P.P1[idx]; s2 += P.P2[idx];
        }
        float sp = __shfl_xor(s, 1, 64), s2p = __shfl_xor(s2, 1, 64);
        float S = s + sp, S2 = s2 + s2p;
        float mean = S * (1.f / 8192.f);
        float var  = S2 * (1.f / 8192.f) - mean * mean;
        float inv  = rsqrtf(var + EPS);
        float a = P.gn_s_w[c] * inv;
        P.AS[b * 64 + c] = a;
        P.BS[b * 64 + c] = P.gn_s_b[c] - mean * a;
    }
    grid.sync();

    // ================= P3: corr = s*t_global + depthwise7x7 -> bf16 NCHW (2048 planes, 8 reps) =================
    {
        float* t4  = (float*)smem;            // 19600 B
        float* ker = (float*)(smem + 19600);  // 196 B
        for (int rep = 0; rep < 8; ++rep) {
            int bc = (blk << 3) + rep;
            __syncthreads();
            for (int i = tid; i < 4900; i += 512) t4[i] = 0.f;
            if (tid < 49) ker[tid] = P.TK[bc * 49 + tid];
            float a = P.AS[bc], bb = P.BS[bc], tg = P.TG[bc];
            __syncthreads();
            const float* sb = P.SRAW + ((long)bc << 12);
            for (int i = tid; i < 4096; i += 512) {
                int y = i >> 6, xx = i & 63;
                float v = a * sb[i] + bb;
                t4[(y + 3) * 70 + xx + 3] = v > 0.f ? v : 0.f;
            }
            __syncthreads();
            int x = tid & 63, ys = (tid >> 6) << 3;
            float acc4[8];
            #pragma unroll
            for (int j = 0; j < 8; ++j) acc4[j] = 0.f;
            #pragma unroll
            for (int kx = 0; kx < 7; ++kx) {
                float col[14];
                #pragma unroll
                for (int j = 0; j < 14; ++j) col[j] = t4[(ys + j) * 70 + x + kx];
                #pragma unroll
                for (int ky = 0; ky < 7; ++ky) {
                    float kv = ker[ky * 7 + kx];
                    #pragma unroll
                    for (int j = 0; j < 8; ++j) acc4[j] += kv * col[j + ky];
                }
            }
            unsigned short* ob = P.CORRB + ((long)bc << 12);
            #pragma unroll
            for (int j = 0; j < 8; ++j) {
                float sval = t4[(ys + j + 3) * 70 + x + 3];
                ob[((ys + j) << 6) + x] = f2bf(acc4[j] + sval * tg);
            }
        }
    }
    grid.sync();

    // ================= P4: corr NCHW bf16 -> NHWC bf16 transpose (2048 jobs, 8 reps) =================
    {
        float (*Tt)[65] = (float(*)[65])smem;   // 16640 B
        for (int rep = 0; rep < 8; ++rep) {
            int job = (blk << 3) + rep;
            int b = job >> 6, py = job & 63;
            __syncthreads();
            const unsigned* src = (const unsigned*)(P.CORRB + (((long)b * 64) << 12) + (py << 6));
            int c = tid >> 3, k4i = tid & 7;
            uint4 u4 = *(const uint4*)(src + ((long)c << 11) + (k4i << 2));
            int pb = k4i << 3;
            Tt[c][pb + 0] = BFLO(u4.x); Tt[c][pb + 1] = BFHI(u4.x);
            Tt[c][pb + 2] = BFLO(u4.y); Tt[c][pb + 3] = BFHI(u4.y);
            Tt[c][pb + 4] = BFLO(u4.z); Tt[c][pb + 5] = BFHI(u4.z);
            Tt[c][pb + 6] = BFLO(u4.w); Tt[c][pb + 7] = BFHI(u4.w);
            __syncthreads();
            int ob8 = tid & 7, pxw = tid >> 3;
            unsigned short* dst = P.CORRT + ((((long)b << 12) + (py << 6)) << 6);
            unsigned w0 = (unsigned)f2bf(Tt[8 * ob8 + 0][pxw]) | ((unsigned)f2bf(Tt[8 * ob8 + 1][pxw]) << 16);
            unsigned w1 = (unsigned)f2bf(Tt[8 * ob8 + 2][pxw]) | ((unsigned)f2bf(Tt[8 * ob8 + 3][pxw]) << 16);
            unsigned w2 = (unsigned)f2bf(Tt[8 * ob8 + 4][pxw]) | ((unsigned)f2bf(Tt[8 * ob8 + 5][pxw]) << 16);
            unsigned w3 = (unsigned)f2bf(Tt[8 * ob8 + 6][pxw]) | ((unsigned)f2bf(Tt[8 * ob8 + 7][pxw]) << 16);
            uint4 val = {w0, w1, w2, w3};
            *(uint4*)(dst + ((long)pxw << 6) + (ob8 << 3)) = val;
        }
    }
    grid.sync();

    // ================= P5: conv3x3 MFMA (NHWC) + fused GN stat partials (512 jobs, 2 reps) =================
    {
        short* tile = (short*)smem;                          // 50688 B
        float (*Ys)[64]  = (float(*)[64])(smem + 50688);     // 2048 B
        float (*Ys2)[64] = (float(*)[64])(smem + 52736);     // 2048 B
        int wave = tid >> 6, lane = tid & 63, q = lane >> 4, l15 = lane & 15;
        for (int rep = 0; rep < 2; ++rep) {
            int job = blk + (rep << 8);
            int b = job >> 4, py0 = (job & 15) << 2;
            __syncthreads();
            for (int u = tid; u < 3168; u += 512) {
                int icblk = u & 7, rc = u >> 3;
                int row = rc / 66, col = rc - 66 * row;
                int py = py0 - 1 + row, px = col - 1;
                short8 v = {0, 0, 0, 0, 0, 0, 0, 0};
                if (py >= 0 && py < 64 && px >= 0 && px < 64)
                    v = *(const short8*)(P.CORRT + (((b << 12) + (py << 6) + px) << 6) + (icblk << 3));
                int sw = icblk ^ (col & 7);
                *(short8*)&tile[(rc << 6) + (sw << 3)] = v;
            }
            __syncthreads();

            floatx4 acc[2][4];
            #pragma unroll
            for (int i = 0; i < 2; ++i)
                #pragma unroll
                for (int ot = 0; ot < 4; ++ot) acc[i][ot] = (floatx4){0.f, 0.f, 0.f, 0.f};

            int pt0 = wave << 1;
            int rowb[2], colb[2];
            #pragma unroll
            for (int i = 0; i < 2; ++i) {
                int p = ((pt0 + i) << 4) + l15;
                rowb[i] = p >> 6;
                colb[i] = p & 63;
            }
            #pragma unroll
            for (int c = 0; c < 18; ++c) {
                const int tap = c >> 1, ky = tap / 3, kx = tap % 3, h = c & 1;
                short8 bfr[4], afr[2];
                #pragma unroll
                for (int ot = 0; ot < 4; ++ot)
                    bfr[ot] = *(const short8*)(P.WPK + ((c << 6) + (ot << 4) + l15) * 32 + (q << 3));
                #pragma unroll
                for (int i = 0; i < 2; ++i) {
                    int row = rowb[i] + ky, col = colb[i] + kx;
                    int sw = ((h << 2) + q) ^ (col & 7);
                    afr[i] = *(const short8*)&tile[((row * 66 + col) << 6) + (sw << 3)];
                }
                #pragma unroll
                for (int i = 0; i < 2; ++i)
                    #pragma unroll
                    for (int ot = 0; ot < 4; ++ot)
                        acc[i][ot] = __builtin_amdgcn_mfma_f32_16x16x32_bf16(afr[i], bfr[ot], acc[i][ot], 0, 0, 0);
            }
            #pragma unroll
            for (int i = 0; i < 2; ++i) {
                #pragma unroll
                for (int r = 0; r < 4; ++r) {
                    int p = ((pt0 + i) << 4) + (q << 2) + r;
                    int py = py0 + (p >> 6), pxc = p & 63;
                    int base = ((b << 12) + (py << 6) + pxc) << 6;
                    #pragma unroll
                    for (int ot = 0; ot < 4; ++ot)
                        P.YRAW[base + (ot << 4) + l15] = f2bf(acc[i][ot][r]);
                }
            }
            #pragma unroll
            for (int ot = 0; ot < 4; ++ot) {
                float s = 0.f, s2 = 0.f;
                #pragma unroll
                for (int i = 0; i < 2; ++i)
                    #pragma unroll
                    for (int r = 0; r < 4; ++r) { float v = acc[i][ot][r]; s += v; s2 += v * v; }
                s += __shfl_xor(s, 16, 64); s2 += __shfl_xor(s2, 16, 64);
                s += __shfl_xor(s, 32, 64); s2 += __shfl_xor(s2, 32, 64);
                if (lane < 16) { Ys[wave][(ot << 4) + lane] = s; Ys2[wave][(ot << 4) + lane] = s2; }
            }
            __syncthreads();
            if (tid < 64) {
                float s = 0.f, s2 = 0.f;
                #pragma unroll
                for (int w = 0; w < 8; ++w) { s += Ys[w][tid]; s2 += Ys2[w][tid]; }
                int idx = (((b << 4) + (job & 15)) << 6) + tid;
                P.P1[idx] = s; P.P2[idx] = s2;
            }
        }
    }
    grid.sync();

    // ================= P6: finalize y-GN coefs =================
    if (blk < 32 && tid < 64) {
        int b = blk, c = tid;
        float s = 0.f, s2 = 0.f;
        for (int t = 0; t < 16; ++t) {
            int idx = (((b << 4) + t) << 6) + c;
            s += P.P1[idx]; s2 += P.P2[idx];
        }
        float sp = __shfl_xor(s, 1, 64), s2p = __shfl_xor(s2, 1, 64);
        float S = s + sp, S2 = s2 + s2p;
        float mean = S * (1.f / 8192.f);
        float var  = S2 * (1.f / 8192.f) - mean * mean;
        float inv  = rsqrtf(var + EPS);
        float a = P.gn_p_w[c] * inv;
        P.AY[b * 64 + c] = a;
        P.BY[b * 64 + c] = P.gn_p_b[c] - mean * a;
    }
    grid.sync();

    // ================= P7: epilogue (256 jobs, 1 per block, 8 waves) =================
    {
        int b = blk >> 3;
        int px0 = (blk & 7) << 9;
        int wave = tid >> 6, lane = tid & 63;
        int ocp = lane & 31, ph = lane >> 5;
        int c0 = 2 * ocp;
        float a0 = P.AY[b * 64 + c0],     b0 = P.BY[b * 64 + c0],     w20 = P.w_p2[c0];
        float a1 = P.AY[b * 64 + c0 + 1], b1 = P.BY[b * 64 + c0 + 1], w21 = P.w_p2[c0 + 1];
        float bias = P.b_p2[0];
        const unsigned* yp = (const unsigned*)P.YRAW;
        for (int i = 0; i < 32; ++i) {
            int px = px0 + (i << 4) + (wave << 1) + ph;
            unsigned u = yp[(((b << 12) + px) << 5) + ocp];
            float f0 = bf2f((unsigned short)(u & 0xFFFF));
            float f1 = bf2f((unsigned short)(u >> 16));
            float v0 = a0 * f0 + b0; v0 = v0 > 0.f ? v0 : 0.f;
            float v1 = a1 * f1 + b1; v1 = v1 > 0.f ? v1 : 0.f;
            float val = w20 * v0 + w21 * v1;
            #pragma unroll
            for (int m = 16; m >= 1; m >>= 1) val += __shfl_xor(val, m, 64);
            if (ocp == 0) P.out[(b << 12) + px] = val + bias;
        }
    }
}

extern "C" void kernel_launch(void* const* d_in, const int* in_sizes, int n_in,
                              void* d_out, int out_size, void* d_ws, size_t ws_size,
                              hipStream_t stream)
{
    float* ws = (float*)d_ws;

    Params prm;
    prm.tmpl   = (const float*)d_in[0];
    prm.search = (const float*)d_in[1];
    prm.w_t    = (const float*)d_in[2];
    prm.gn_t_w = (const float*)d_in[3];
    prm.gn_t_b = (const float*)d_in[4];
    prm.w_s    = (const float*)d_in[5];
    prm.gn_s_w = (const float*)d_in[6];
    prm.gn_s_b = (const float*)d_in[7];
    prm.w_p1   = (const float*)d_in[8];
    prm.gn_p_w = (const float*)d_in[9];
    prm.gn_p_b = (const float*)d_in[10];
    prm.w_p2   = (const float*)d_in[11];
    prm.b_p2   = (const float*)d_in[12];
    prm.out    = (float*)d_out;

    prm.TG = ws;                         // 2048
    prm.TK = ws + 2048;                  // 100352 -> ends 102400
    prm.AS = ws + 102400;                // 2048
    prm.BS = ws + 104448;                // 2048
    prm.AY = ws + 106496;                // 2048
    prm.BY = ws + 108544;                // 2048 -> ends 110592
    prm.P1 = ws + 110592;                // 32768 -> ends 143360
    prm.P2 = ws + 143360;                // 32768 -> ends 176128
    prm.WPK = (unsigned short*)(ws + 176128);     // 36864 bf16
    prm.SRAW = ws + 196608;                       // 8388608 floats (32 MB)
    prm.CORRB = (unsigned short*)(ws + 8585216);  // 4194304 bf16 (8 MB)
    // overlays (timeline-disjoint, separated by grid.sync):
    prm.WSB   = prm.CORRB;                               // written P0, read P1; overwritten P3
    prm.YRAW  = (unsigned short*)prm.SRAW;               // written P5 (SRAW dead after P3)
    prm.CORRT = (unsigned short*)(prm.SRAW + 4194304);   // written P4, read P5

    void* args[] = { (void*)&prm };
    hipLaunchCooperativeKernel((const void*)fused, dim3(256), dim3(512), args, 0, stream);
}

// Round 3
// 336.882 us; speedup vs baseline: 1.8127x; 1.8127x over previous
//
#include <hip/hip_runtime.h>

#define EPS 1e-5f

// B=32, C=256, CC=64, template 14x14, search 64x64, K=7, 32 groups (2ch/group)

typedef __attribute__((ext_vector_type(8))) short short8;
typedef __attribute__((ext_vector_type(4))) float floatx4;

__device__ __forceinline__ unsigned short f2bf(float x) {
    union { float f; unsigned u; } v; v.f = x;
    unsigned r = v.u + 0x7FFFu + ((v.u >> 16) & 1u);   // RNE
    return (unsigned short)(r >> 16);
}
__device__ __forceinline__ float bf2f(unsigned short h) {
    union { unsigned u; float f; } v; v.u = ((unsigned)h) << 16;
    return v.f;
}

// ---------------- K1: template path (grid 256 = b x oc-eighth, 8 oc/block) ----------------
__global__ __launch_bounds__(256) void k1_template(
    const float* __restrict__ tmpl, const float* __restrict__ w_t,
    const float* __restrict__ gnw, const float* __restrict__ gnb,
    float* __restrict__ t_global, float* __restrict__ t_kernel)
{
    int b = blockIdx.x >> 3, h = blockIdx.x & 7;   // h: eighth of oc (8 oc)
    int tid = threadIdx.x;
    __shared__ float Xs[32][200];   // 32-ic chunk x 196 px (pad 200)
    __shared__ float T0[8][200];
    __shared__ float sums[8], sumsq[8], Ac[8], Bb[8];
    float acc[8];
    #pragma unroll
    for (int o = 0; o < 8; ++o) acc[o] = 0.f;
    const float* wb = w_t + (h * 8) * 256;         // uniform -> s_load
    const float* tb = tmpl + b * 50176;
    int p = tid;
    for (int chunk = 0; chunk < 8; ++chunk) {
        __syncthreads();
        #pragma unroll
        for (int j = 0; j < 7; ++j) {
            int f4 = tid + (j << 8);
            if (f4 < 1568) {                        // 32 rows x 49 float4
                int ic = f4 / 49, px4 = (f4 - ic * 49) << 2;
                float4 v = *(const float4*)(tb + (chunk * 32 + ic) * 196 + px4);
                *(float4*)&Xs[ic][px4] = v;
            }
        }
        __syncthreads();
        if (p < 196) {
            for (int cc = 0; cc < 32; ++cc) {
                float xv = Xs[cc][p];
                #pragma unroll
                for (int o = 0; o < 8; ++o)
                    acc[o] += xv * wb[o * 256 + chunk * 32 + cc];
            }
        }
    }
    __syncthreads();
    if (p < 196) {
        #pragma unroll
        for (int o = 0; o < 8; ++o) T0[o][p] = acc[o];
    }
    __syncthreads();
    if (tid < 128) {   // 16 lanes per channel
        int c = tid >> 4, part = tid & 15;
        float s = 0.f, s2 = 0.f;
        for (int qq = part; qq < 196; qq += 16) { float v = T0[c][qq]; s += v; s2 += v * v; }
        #pragma unroll
        for (int off = 1; off < 16; off <<= 1) {
            s += __shfl_xor(s, off, 16); s2 += __shfl_xor(s2, off, 16);
        }
        if (part == 0) { sums[c] = s; sumsq[c] = s2; }
    }
    __syncthreads();
    if (tid < 4) {   // group = channel pair, both in this block
        float S  = sums[2 * tid] + sums[2 * tid + 1];
        float S2 = sumsq[2 * tid] + sumsq[2 * tid + 1];
        float mean = S * (1.f / 392.f);
        float var  = S2 * (1.f / 392.f) - mean * mean;
        float inv  = rsqrtf(var + EPS);
        for (int e = 0; e < 2; ++e) {
            int c = 2 * tid + e, gc = h * 8 + c;
            float a = gnw[gc] * inv;
            Ac[c] = a; Bb[c] = gnb[gc] - mean * a;
        }
    }
    __syncthreads();
    if (p < 196) {
        #pragma unroll
        for (int o = 0; o < 8; ++o) {
            float v = Ac[o] * T0[o][p] + Bb[o];
            T0[o][p] = v > 0.f ? v : 0.f;
        }
    }
    __syncthreads();
    if (tid < 128) {
        int c = tid >> 4, part = tid & 15, gc = h * 8 + c;
        float s = 0.f;
        for (int qq = part; qq < 196; qq += 16) s += T0[c][qq];
        #pragma unroll
        for (int off = 1; off < 16; off <<= 1) s += __shfl_xor(s, off, 16);
        if (part == 0) t_global[b * 64 + gc] = s * (1.f / 196.f);
        for (int t = part; t < 49; t += 16) {
            int ky = t / 7, kx = t - 7 * ky;
            float v = T0[c][(2 * ky) * 14 + 2 * kx]     + T0[c][(2 * ky) * 14 + 2 * kx + 1]
                    + T0[c][(2 * ky + 1) * 14 + 2 * kx] + T0[c][(2 * ky + 1) * 14 + 2 * kx + 1];
            t_kernel[(b * 64 + gc) * 49 + t] = v * 0.25f;
        }
    }
}

// ---------------- K_PACK: w_s and w_p1 fp32 -> bf16 prepack ----------------
__global__ __launch_bounds__(256) void k_pack(
    const float* __restrict__ w_s, unsigned short* __restrict__ wsb,
    const float* __restrict__ w1, unsigned short* __restrict__ wpk)
{
    int blk = blockIdx.x;
    if (blk < 64) {
        int i = blk * 256 + threadIdx.x;
        wsb[i] = f2bf(w_s[i]);
    } else {
        int i = (blk - 64) * 256 + threadIdx.x;
        if (i < 36864) {
            int c = i >> 11;
            int rem = i & 2047;
            int oc = rem >> 5;
            int k = rem & 31;
            int tap = c >> 1;
            int ic = ((c & 1) << 5) + k;
            wpk[i] = f2bf(w1[oc * 576 + ic * 9 + tap]);
        }
    }
}

// ---------------- K2: search conv1x1 via bf16 MFMA, 128-px tiles, float4 staging ----------------
// grid (32 px-tiles, 32 b). Block 256 thr (4 waves): 128 px x 64 oc, K=256.
// Epilogue: per-oc partial sum/sumsq over 128 px -> P1/P2[(b*32+tile)*64+oc].
__global__ __launch_bounds__(256) void k2_mfma(
    const float* __restrict__ x, const unsigned short* __restrict__ wsb,
    float* __restrict__ sraw, float* __restrict__ P1, float* __restrict__ P2)
{
    int b = blockIdx.y, p0 = blockIdx.x << 7;
    int tid = threadIdx.x;
    int wave = tid >> 6, lane = tid & 63, q = lane >> 4, l15 = lane & 15;
    __shared__ short tile[128 * 64];   // [px 128][ic 64] bf16, icblk xor-swizzled by px&7
    __shared__ float Ps[4][64], Ps2[4][64];

    floatx4 acc[2][4];
    #pragma unroll
    for (int i = 0; i < 2; ++i)
        #pragma unroll
        for (int mt = 0; mt < 4; ++mt) acc[i][mt] = (floatx4){0.f, 0.f, 0.f, 0.f};

    int pxq = (tid & 31) << 2;     // px base (4 consecutive px per thread)
    int icr = tid >> 5;            // ic group 0..7 (8 consecutive ic per thread)
    const float* xb = x + ((long)b << 20) + p0 + pxq;
    for (int chunk = 0; chunk < 4; ++chunk) {           // 64 ic per chunk
        __syncthreads();
        float4 L[8];
        #pragma unroll
        for (int i = 0; i < 8; ++i)
            L[i] = *(const float4*)(xb + ((long)((chunk << 6) + (icr << 3) + i) << 12));
        #pragma unroll
        for (int j = 0; j < 4; ++j) {
            int px = pxq + j;
            short8 s8;
            #pragma unroll
            for (int e = 0; e < 8; ++e) s8[e] = (short)f2bf(((const float*)&L[e])[j]);
            int sw = icr ^ (px & 7);
            *(short8*)&tile[(px << 6) + (sw << 3)] = s8;
        }
        __syncthreads();
        #pragma unroll
        for (int kq = 0; kq < 2; ++kq) {                // 32-ic MFMA chunks
            short8 afr[4], bfr[2];
            int kbase = (chunk << 6) + (kq << 5) + (q << 3);
            #pragma unroll
            for (int mt = 0; mt < 4; ++mt)
                afr[mt] = *(const short8*)(wsb + ((mt << 4) + l15) * 256 + kbase);
            #pragma unroll
            for (int i = 0; i < 2; ++i) {
                int px = (((wave << 1) + i) << 4) + l15;
                int sw = ((kq << 2) + q) ^ (px & 7);
                bfr[i] = *(const short8*)&tile[(px << 6) + (sw << 3)];
            }
            #pragma unroll
            for (int i = 0; i < 2; ++i)
                #pragma unroll
                for (int mt = 0; mt < 4; ++mt)
                    acc[i][mt] = __builtin_amdgcn_mfma_f32_16x16x32_bf16(afr[mt], bfr[i], acc[i][mt], 0, 0, 0);
        }
    }
    // D: col(lane&15)=px-in-frag, row(q*4+r)=oc-in-tile
    float* ob = sraw + ((long)b << 18) + p0;
    #pragma unroll
    for (int i = 0; i < 2; ++i) {
        int pxb = ((wave << 1) + i) << 4;
        #pragma unroll
        for (int mt = 0; mt < 4; ++mt)
            #pragma unroll
            for (int r = 0; r < 4; ++r) {
                int oc = (mt << 4) + (q << 2) + r;
                ob[(oc << 12) + pxb + l15] = acc[i][mt][r];
            }
    }
    // fused GN stat partials
    #pragma unroll
    for (int mt = 0; mt < 4; ++mt) {
        #pragma unroll
        for (int r = 0; r < 4; ++r) {
            float s = 0.f, s2 = 0.f;
            #pragma unroll
            for (int i = 0; i < 2; ++i) { float v = acc[i][mt][r]; s += v; s2 += v * v; }
            #pragma unroll
            for (int off = 1; off < 16; off <<= 1) {
                s  += __shfl_xor(s, off, 64);
                s2 += __shfl_xor(s2, off, 64);
            }
            if (l15 == 0) {
                int oc = (mt << 4) + (q << 2) + r;
                Ps[wave][oc] = s; Ps2[wave][oc] = s2;
            }
        }
    }
    __syncthreads();
    if (tid < 64) {
        float s  = Ps[0][tid] + Ps[1][tid] + Ps[2][tid] + Ps[3][tid];
        float s2 = Ps2[0][tid] + Ps2[1][tid] + Ps2[2][tid] + Ps2[3][tid];
        int idx = (((b << 5) + blockIdx.x) << 6) + tid;
        P1[idx] = s; P2[idx] = s2;
    }
}

// ---------------- K4: corr = s*t_global + depthwise7x7 -> bf16 NCHW (inline s-GN finalize) ----------------
__global__ __launch_bounds__(256) void k4_corr(
    const float* __restrict__ sraw, const float* __restrict__ P1, const float* __restrict__ P2,
    const float* __restrict__ gnw, const float* __restrict__ gnb,
    const float* __restrict__ t_global, const float* __restrict__ t_kernel,
    unsigned short* __restrict__ corr)
{
    int bc = blockIdx.x;
    int b = bc >> 6, c = bc & 63;
    int tid = threadIdx.x;
    __shared__ float t4[70 * 70];
    __shared__ float ker[49];
    __shared__ float fin4[4];
    __shared__ float sAB[2];
    if (tid < 32) {   // finalize this block's GN coefs from 32 tile-partials x 2 channels
        int ch = (c & ~1) + (tid >> 4), k = tid & 15;
        int base = ((b << 5) + k) << 6;
        float s  = P1[base + ch] + P1[base + (16 << 6) + ch];
        float s2 = P2[base + ch] + P2[base + (16 << 6) + ch];
        #pragma unroll
        for (int off = 1; off < 16; off <<= 1) {
            s += __shfl_xor(s, off, 16); s2 += __shfl_xor(s2, off, 16);
        }
        if (k == 0) { fin4[tid >> 4] = s; fin4[2 + (tid >> 4)] = s2; }
    }
    for (int i = tid; i < 4900; i += 256) t4[i] = 0.f;
    if (tid < 49) ker[tid] = t_kernel[bc * 49 + tid];
    __syncthreads();
    if (tid == 0) {
        float S = fin4[0] + fin4[1], S2 = fin4[2] + fin4[3];
        float mean = S * (1.f / 8192.f);
        float var  = S2 * (1.f / 8192.f) - mean * mean;
        float inv  = rsqrtf(var + EPS);
        float a = gnw[c] * inv;
        sAB[0] = a; sAB[1] = gnb[c] - mean * a;
    }
    __syncthreads();
    float a = sAB[0], bb = sAB[1], tg = t_global[bc];
    const float4* sb4 = (const float4*)(sraw + ((long)bc << 12));
    for (int i4 = tid; i4 < 1024; i4 += 256) {
        float4 v4 = sb4[i4];
        int y = i4 >> 4, xx = (i4 & 15) << 2;
        float* dst = &t4[(y + 3) * 70 + xx + 3];
        float v;
        v = a * v4.x + bb; dst[0] = v > 0.f ? v : 0.f;
        v = a * v4.y + bb; dst[1] = v > 0.f ? v : 0.f;
        v = a * v4.z + bb; dst[2] = v > 0.f ? v : 0.f;
        v = a * v4.w + bb; dst[3] = v > 0.f ? v : 0.f;
    }
    __syncthreads();
    int x = tid & 63, ys = (tid >> 6) << 4;
    float acc[16];
    #pragma unroll
    for (int j = 0; j < 16; ++j) acc[j] = 0.f;
    #pragma unroll
    for (int kx = 0; kx < 7; ++kx) {
        float col[22];
        #pragma unroll
        for (int j = 0; j < 22; ++j) col[j] = t4[(ys + j) * 70 + x + kx];
        #pragma unroll
        for (int ky = 0; ky < 7; ++ky) {
            float kv = ker[ky * 7 + kx];
            #pragma unroll
            for (int j = 0; j < 16; ++j) acc[j] += kv * col[j + ky];
        }
    }
    unsigned short* ob = corr + ((long)bc << 12);
    #pragma unroll
    for (int j = 0; j < 16; ++j) {
        float sval = t4[(ys + j + 3) * 70 + x + 3];
        ob[((ys + j) << 6) + x] = f2bf(acc[j] + sval * tg);
    }
}

// ---------------- K_T: corr NCHW bf16 -> NHWC bf16 transpose ----------------
__global__ __launch_bounds__(256) void k_t(
    const unsigned short* __restrict__ corr, unsigned short* __restrict__ corrT)
{
    int py = blockIdx.x, b = blockIdx.y;
    int tid = threadIdx.x;
    __shared__ float T[64][65];
    {
        int c0 = tid >> 5, pxp = tid & 31;   // uint-packed loads: 2 px per thread
        const unsigned* src = (const unsigned*)(corr + (((long)b * 64) << 12) + (py << 6)) + pxp;
        #pragma unroll
        for (int i = 0; i < 8; ++i) {
            int c = c0 + (i << 3);
            unsigned u = src[(long)c << 11];   // c-stride 4096 shorts = 2048 uints
            T[c][2 * pxp]     = bf2f((unsigned short)(u & 0xFFFF));
            T[c][2 * pxp + 1] = bf2f((unsigned short)(u >> 16));
        }
    }
    __syncthreads();
    int ob = tid & 7, pxw = tid >> 3;
    unsigned short* dst = corrT + ((((b << 12)) + (py << 6)) << 6);
    #pragma unroll
    for (int i = 0; i < 2; ++i) {
        int p = pxw + (i << 5);
        unsigned w0 = (unsigned)f2bf(T[8 * ob + 0][p]) | ((unsigned)f2bf(T[8 * ob + 1][p]) << 16);
        unsigned w1 = (unsigned)f2bf(T[8 * ob + 2][p]) | ((unsigned)f2bf(T[8 * ob + 3][p]) << 16);
        unsigned w2 = (unsigned)f2bf(T[8 * ob + 4][p]) | ((unsigned)f2bf(T[8 * ob + 5][p]) << 16);
        unsigned w3 = (unsigned)f2bf(T[8 * ob + 6][p]) | ((unsigned)f2bf(T[8 * ob + 7][p]) << 16);
        uint4 val = {w0, w1, w2, w3};
        *(uint4*)(dst + ((long)p << 6) + (ob << 3)) = val;
    }
}

// ---------------- K5: conv3x3 via bf16 MFMA (NHWC), 2-row tiles + fused GN stat partials ----------------
__global__ __launch_bounds__(256) void k5_mfma(
    const unsigned short* __restrict__ corrT, const unsigned short* __restrict__ wpk,
    unsigned short* __restrict__ y, float* __restrict__ P1, float* __restrict__ P2)
{
    int b = blockIdx.y, py0 = blockIdx.x << 1;
    int tid = threadIdx.x;
    int wave = tid >> 6, lane = tid & 63, q = lane >> 4, l15 = lane & 15;
    __shared__ short tile[16896];   // [row 4][col 66][ic 64] bf16, xor-swizzled (33792 B)
    __shared__ float Ys[4][64], Ys2[4][64];

    for (int u = tid; u < 2112; u += 256) {
        int icblk = u & 7, rc = u >> 3;
        int row = rc / 66, col = rc - 66 * row;
        int py = py0 - 1 + row, px = col - 1;
        short8 v = {0, 0, 0, 0, 0, 0, 0, 0};
        if (py >= 0 && py < 64 && px >= 0 && px < 64)
            v = *(const short8*)(corrT + (((b << 12) + (py << 6) + px) << 6) + (icblk << 3));
        int sw = icblk ^ (col & 7);
        *(short8*)&tile[(rc << 6) + (sw << 3)] = v;
    }
    __syncthreads();

    floatx4 acc[2][4];
    #pragma unroll
    for (int i = 0; i < 2; ++i)
        #pragma unroll
        for (int ot = 0; ot < 4; ++ot) acc[i][ot] = (floatx4){0.f, 0.f, 0.f, 0.f};

    int pt0 = wave << 1;
    int rowb[2], colb[2];
    #pragma unroll
    for (int i = 0; i < 2; ++i) {
        int p = ((pt0 + i) << 4) + l15;
        rowb[i] = p >> 6;
        colb[i] = p & 63;
    }
    #pragma unroll
    for (int c = 0; c < 18; ++c) {
        const int tap = c >> 1, ky = tap / 3, kx = tap % 3, h = c & 1;
        short8 bfr[4], afr[2];
        #pragma unroll
        for (int ot = 0; ot < 4; ++ot)
            bfr[ot] = *(const short8*)(wpk + ((c << 6) + (ot << 4) + l15) * 32 + (q << 3));
        #pragma unroll
        for (int i = 0; i < 2; ++i) {
            int row = rowb[i] + ky, col = colb[i] + kx;
            int sw = ((h << 2) + q) ^ (col & 7);
            afr[i] = *(const short8*)&tile[((row * 66 + col) << 6) + (sw << 3)];
        }
        #pragma unroll
        for (int i = 0; i < 2; ++i)
            #pragma unroll
            for (int ot = 0; ot < 4; ++ot)
                acc[i][ot] = __builtin_amdgcn_mfma_f32_16x16x32_bf16(afr[i], bfr[ot], acc[i][ot], 0, 0, 0);
    }
    #pragma unroll
    for (int i = 0; i < 2; ++i) {
        #pragma unroll
        for (int r = 0; r < 4; ++r) {
            int p = ((pt0 + i) << 4) + (q << 2) + r;
            int py = py0 + (p >> 6), pxc = p & 63;
            int base = ((b << 12) + (py << 6) + pxc) << 6;
            #pragma unroll
            for (int ot = 0; ot < 4; ++ot)
                y[base + (ot << 4) + l15] = f2bf(acc[i][ot][r]);
        }
    }
    // fused GN stat partials: lane holds oc = ot*16 + l15
    #pragma unroll
    for (int ot = 0; ot < 4; ++ot) {
        float s = 0.f, s2 = 0.f;
        #pragma unroll
        for (int i = 0; i < 2; ++i)
            #pragma unroll
            for (int r = 0; r < 4; ++r) { float v = acc[i][ot][r]; s += v; s2 += v * v; }
        s += __shfl_xor(s, 16, 64); s2 += __shfl_xor(s2, 16, 64);
        s += __shfl_xor(s, 32, 64); s2 += __shfl_xor(s2, 32, 64);
        if (lane < 16) { Ys[wave][(ot << 4) + lane] = s; Ys2[wave][(ot << 4) + lane] = s2; }
    }
    __syncthreads();
    if (tid < 64) {
        float s  = Ys[0][tid] + Ys[1][tid] + Ys[2][tid] + Ys[3][tid];
        float s2 = Ys2[0][tid] + Ys2[1][tid] + Ys2[2][tid] + Ys2[3][tid];
        int idx = (((b << 5) + blockIdx.x) << 6) + tid;
        P1[idx] = s; P2[idx] = s2;
    }
}

// ---------------- K6: epilogue on NHWC bf16 y (inline y-GN finalize) ----------------
__global__ __launch_bounds__(256) void k6_nhwc(
    const unsigned short* __restrict__ y, const float* __restrict__ P1, const float* __restrict__ P2,
    const float* __restrict__ gnw, const float* __restrict__ gnb,
    const float* __restrict__ w2, const float* __restrict__ b2, float* __restrict__ out)
{
    int b = blockIdx.y;
    int px0 = blockIdx.x << 7;
    int tid = threadIdx.x, wave = tid >> 6, lane = tid & 63;
    __shared__ float sA[64], sB[64];
    if (tid < 64) {
        int c = tid;
        float s = 0.f, s2 = 0.f;
        for (int t = 0; t < 32; ++t) {
            int idx = (((b << 5) + t) << 6) + c;
            s += P1[idx]; s2 += P2[idx];
        }
        float sp = __shfl_xor(s, 1, 64), s2p = __shfl_xor(s2, 1, 64);
        float S = s + sp, S2 = s2 + s2p;
        float mean = S * (1.f / 8192.f);
        float var  = S2 * (1.f / 8192.f) - mean * mean;
        float inv  = rsqrtf(var + EPS);
        float a = gnw[c] * inv;
        sA[c] = a; sB[c] = gnb[c] - mean * a;
    }
    __syncthreads();
    int ocp = lane & 31, ph = lane >> 5;
    int c0 = 2 * ocp;
    float a0 = sA[c0],     b0 = sB[c0],     w20 = w2[c0];
    float a1 = sA[c0 + 1], b1 = sB[c0 + 1], w21 = w2[c0 + 1];
    float bias = b2[0];
    const unsigned* yp = (const unsigned*)y;
    for (int i = 0; i < 16; ++i) {
        int px = px0 + (i << 3) + (wave << 1) + ph;
        unsigned u = yp[(((b << 12) + px) << 5) + ocp];
        float f0 = bf2f((unsigned short)(u & 0xFFFF));
        float f1 = bf2f((unsigned short)(u >> 16));
        float v0 = a0 * f0 + b0; v0 = v0 > 0.f ? v0 : 0.f;
        float v1 = a1 * f1 + b1; v1 = v1 > 0.f ? v1 : 0.f;
        float val = w20 * v0 + w21 * v1;
        #pragma unroll
        for (int m = 16; m >= 1; m >>= 1) val += __shfl_xor(val, m, 64);
        if (ocp == 0) out[(b << 12) + px] = val + bias;
    }
}

extern "C" void kernel_launch(void* const* d_in, const int* in_sizes, int n_in,
                              void* d_out, int out_size, void* d_ws, size_t ws_size,
                              hipStream_t stream)
{
    const float* tmpl   = (const float*)d_in[0];
    const float* search = (const float*)d_in[1];
    const float* w_t    = (const float*)d_in[2];
    const float* gn_t_w = (const float*)d_in[3];
    const float* gn_t_b = (const float*)d_in[4];
    const float* w_s    = (const float*)d_in[5];
    const float* gn_s_w = (const float*)d_in[6];
    const float* gn_s_b = (const float*)d_in[7];
    const float* w_p1   = (const float*)d_in[8];
    const float* gn_p_w = (const float*)d_in[9];
    const float* gn_p_b = (const float*)d_in[10];
    const float* w_p2   = (const float*)d_in[11];
    const float* b_p2   = (const float*)d_in[12];
    float* out = (float*)d_out;
    float* ws  = (float*)d_ws;

    float* TG   = ws;                    // 2048
    float* TK   = ws + 2048;             // 100352 -> ends 102400
    float* P1   = ws + 102400;           // 65536 (32b x 32 tiles x 64 oc) -> ends 167936
    float* P2   = ws + 167936;           // 65536 -> ends 233472
    unsigned short* WPK = (unsigned short*)(ws + 233472);   // 36864 bf16 -> ends 251904
    float* SRAW = ws + 262144;           // 8388608 floats (32 MB) -> ends 8650752
    unsigned short* CORRB = (unsigned short*)(ws + 8650752); // 4194304 bf16 (8 MB)
    // overlays (timeline-disjoint):
    unsigned short* WSB   = (unsigned short*)CORRB;          // k_pack writes, k2 reads; k4 overwrites
    unsigned short* YRAW  = (unsigned short*)SRAW;           // k5 writes after SRAW dead (k4 last reader)
    unsigned short* CORRT = (unsigned short*)(SRAW + 4194304);

    k_pack<<<208, 256, 0, stream>>>(w_s, WSB, w_p1, WPK);
    k1_template<<<256, 256, 0, stream>>>(tmpl, w_t, gn_t_w, gn_t_b, TG, TK);
    k2_mfma<<<dim3(32, 32), 256, 0, stream>>>(search, WSB, SRAW, P1, P2);
    k4_corr<<<2048, 256, 0, stream>>>(SRAW, P1, P2, gn_s_w, gn_s_b, TG, TK, CORRB);
    k_t<<<dim3(64, 32), 256, 0, stream>>>(CORRB, CORRT);
    k5_mfma<<<dim3(32, 32), 256, 0, stream>>>(CORRT, WPK, YRAW, P1, P2);
    k6_nhwc<<<dim3(32, 32), 256, 0, stream>>>(YRAW, P1, P2, gn_p_w, gn_p_b, w_p2, b_p2, out);
}

// Round 4
// 329.392 us; speedup vs baseline: 1.8539x; 1.0227x over previous
//
#include <hip/hip_runtime.h>

#define EPS 1e-5f

// B=32, C=256, CC=64, template 14x14, search 64x64, K=7, 32 groups (2ch/group)

typedef __attribute__((ext_vector_type(8))) short short8;
typedef __attribute__((ext_vector_type(4))) float floatx4;

__device__ __forceinline__ unsigned short f2bf(float x) {
    union { float f; unsigned u; } v; v.f = x;
    unsigned r = v.u + 0x7FFFu + ((v.u >> 16) & 1u);   // RNE
    return (unsigned short)(r >> 16);
}
__device__ __forceinline__ float bf2f(unsigned short h) {
    union { unsigned u; float f; } v; v.u = ((unsigned)h) << 16;
    return v.f;
}

// ---------------- K1: template path (grid 256 = b x oc-eighth, 8 oc/block) ----------------
__global__ __launch_bounds__(256) void k1_template(
    const float* __restrict__ tmpl, const float* __restrict__ w_t,
    const float* __restrict__ gnw, const float* __restrict__ gnb,
    float* __restrict__ t_global, float* __restrict__ t_kernel)
{
    int b = blockIdx.x >> 3, h = blockIdx.x & 7;   // h: eighth of oc (8 oc)
    int tid = threadIdx.x;
    __shared__ float Xs[32][200];   // 32-ic chunk x 196 px (pad 200)
    __shared__ float T0[8][200];
    __shared__ float sums[8], sumsq[8], Ac[8], Bb[8];
    float acc[8];
    #pragma unroll
    for (int o = 0; o < 8; ++o) acc[o] = 0.f;
    const float* wb = w_t + (h * 8) * 256;         // uniform -> s_load
    const float* tb = tmpl + b * 50176;
    int p = tid;
    for (int chunk = 0; chunk < 8; ++chunk) {
        __syncthreads();
        #pragma unroll
        for (int j = 0; j < 7; ++j) {
            int f4 = tid + (j << 8);
            if (f4 < 1568) {                        // 32 rows x 49 float4
                int ic = f4 / 49, px4 = (f4 - ic * 49) << 2;
                float4 v = *(const float4*)(tb + (chunk * 32 + ic) * 196 + px4);
                *(float4*)&Xs[ic][px4] = v;
            }
        }
        __syncthreads();
        if (p < 196) {
            for (int cc = 0; cc < 32; ++cc) {
                float xv = Xs[cc][p];
                #pragma unroll
                for (int o = 0; o < 8; ++o)
                    acc[o] += xv * wb[o * 256 + chunk * 32 + cc];
            }
        }
    }
    __syncthreads();
    if (p < 196) {
        #pragma unroll
        for (int o = 0; o < 8; ++o) T0[o][p] = acc[o];
    }
    __syncthreads();
    if (tid < 128) {   // 16 lanes per channel
        int c = tid >> 4, part = tid & 15;
        float s = 0.f, s2 = 0.f;
        for (int qq = part; qq < 196; qq += 16) { float v = T0[c][qq]; s += v; s2 += v * v; }
        #pragma unroll
        for (int off = 1; off < 16; off <<= 1) {
            s += __shfl_xor(s, off, 16); s2 += __shfl_xor(s2, off, 16);
        }
        if (part == 0) { sums[c] = s; sumsq[c] = s2; }
    }
    __syncthreads();
    if (tid < 4) {   // group = channel pair, both in this block
        float S  = sums[2 * tid] + sums[2 * tid + 1];
        float S2 = sumsq[2 * tid] + sumsq[2 * tid + 1];
        float mean = S * (1.f / 392.f);
        float var  = S2 * (1.f / 392.f) - mean * mean;
        float inv  = rsqrtf(var + EPS);
        for (int e = 0; e < 2; ++e) {
            int c = 2 * tid + e, gc = h * 8 + c;
            float a = gnw[gc] * inv;
            Ac[c] = a; Bb[c] = gnb[gc] - mean * a;
        }
    }
    __syncthreads();
    if (p < 196) {
        #pragma unroll
        for (int o = 0; o < 8; ++o) {
            float v = Ac[o] * T0[o][p] + Bb[o];
            T0[o][p] = v > 0.f ? v : 0.f;
        }
    }
    __syncthreads();
    if (tid < 128) {
        int c = tid >> 4, part = tid & 15, gc = h * 8 + c;
        float s = 0.f;
        for (int qq = part; qq < 196; qq += 16) s += T0[c][qq];
        #pragma unroll
        for (int off = 1; off < 16; off <<= 1) s += __shfl_xor(s, off, 16);
        if (part == 0) t_global[b * 64 + gc] = s * (1.f / 196.f);
        for (int t = part; t < 49; t += 16) {
            int ky = t / 7, kx = t - 7 * ky;
            float v = T0[c][(2 * ky) * 14 + 2 * kx]     + T0[c][(2 * ky) * 14 + 2 * kx + 1]
                    + T0[c][(2 * ky + 1) * 14 + 2 * kx] + T0[c][(2 * ky + 1) * 14 + 2 * kx + 1];
            t_kernel[(b * 64 + gc) * 49 + t] = v * 0.25f;
        }
    }
}

// ---------------- K_PACK: w_s and w_p1 fp32 -> bf16 prepack ----------------
__global__ __launch_bounds__(256) void k_pack(
    const float* __restrict__ w_s, unsigned short* __restrict__ wsb,
    const float* __restrict__ w1, unsigned short* __restrict__ wpk)
{
    int blk = blockIdx.x;
    if (blk < 64) {
        int i = blk * 256 + threadIdx.x;
        wsb[i] = f2bf(w_s[i]);
    } else {
        int i = (blk - 64) * 256 + threadIdx.x;
        if (i < 36864) {
            int c = i >> 11;
            int rem = i & 2047;
            int oc = rem >> 5;
            int k = rem & 31;
            int tap = c >> 1;
            int ic = ((c & 1) << 5) + k;
            wpk[i] = f2bf(w1[oc * 576 + ic * 9 + tap]);
        }
    }
}

// ---------------- K2: search conv1x1 via bf16 MFMA, 128-px tiles, reg-prefetch ----------------
// grid (32 px-tiles, 32 b). Block 256 thr (4 waves): 128 px x 64 oc, K=256.
// Next-chunk global loads issued BEFORE the MFMA consumes the current LDS tile.
__global__ __launch_bounds__(256) void k2_mfma(
    const float* __restrict__ x, const unsigned short* __restrict__ wsb,
    float* __restrict__ sraw, float* __restrict__ P1, float* __restrict__ P2)
{
    int b = blockIdx.y, p0 = blockIdx.x << 7;
    int tid = threadIdx.x;
    int wave = tid >> 6, lane = tid & 63, q = lane >> 4, l15 = lane & 15;
    __shared__ short tile[128 * 64];   // [px 128][ic 64] bf16, icblk xor-swizzled by px&7
    __shared__ float Ps[4][64], Ps2[4][64];

    floatx4 acc[2][4];
    #pragma unroll
    for (int i = 0; i < 2; ++i)
        #pragma unroll
        for (int mt = 0; mt < 4; ++mt) acc[i][mt] = (floatx4){0.f, 0.f, 0.f, 0.f};

    int pxq = (tid & 31) << 2;     // px base (4 consecutive px per thread)
    int icr = tid >> 5;            // ic group 0..7 (8 consecutive ic per thread)
    const float* xb = x + ((long)b << 20) + p0 + pxq;
    float4 L[8];
    #pragma unroll
    for (int i = 0; i < 8; ++i)
        L[i] = *(const float4*)(xb + ((long)((icr << 3) + i) << 12));
    for (int chunk = 0; chunk < 4; ++chunk) {           // 64 ic per chunk
        __syncthreads();   // prior MFMA reads of tile complete
        #pragma unroll
        for (int j = 0; j < 4; ++j) {
            int px = pxq + j;
            short8 s8;
            #pragma unroll
            for (int e = 0; e < 8; ++e) s8[e] = (short)f2bf(((const float*)&L[e])[j]);
            int sw = icr ^ (px & 7);
            *(short8*)&tile[(px << 6) + (sw << 3)] = s8;
        }
        __syncthreads();
        if (chunk < 3) {   // prefetch next chunk while MFMA runs
            #pragma unroll
            for (int i = 0; i < 8; ++i)
                L[i] = *(const float4*)(xb + ((long)(((chunk + 1) << 6) + (icr << 3) + i) << 12));
        }
        #pragma unroll
        for (int kq = 0; kq < 2; ++kq) {                // 32-ic MFMA chunks
            short8 afr[4], bfr[2];
            int kbase = (chunk << 6) + (kq << 5) + (q << 3);
            #pragma unroll
            for (int mt = 0; mt < 4; ++mt)
                afr[mt] = *(const short8*)(wsb + ((mt << 4) + l15) * 256 + kbase);
            #pragma unroll
            for (int i = 0; i < 2; ++i) {
                int px = (((wave << 1) + i) << 4) + l15;
                int sw = ((kq << 2) + q) ^ (px & 7);
                bfr[i] = *(const short8*)&tile[(px << 6) + (sw << 3)];
            }
            #pragma unroll
            for (int i = 0; i < 2; ++i)
                #pragma unroll
                for (int mt = 0; mt < 4; ++mt)
                    acc[i][mt] = __builtin_amdgcn_mfma_f32_16x16x32_bf16(afr[mt], bfr[i], acc[i][mt], 0, 0, 0);
        }
    }
    // D: col(lane&15)=px-in-frag, row(q*4+r)=oc-in-tile
    float* ob = sraw + ((long)b << 18) + p0;
    #pragma unroll
    for (int i = 0; i < 2; ++i) {
        int pxb = ((wave << 1) + i) << 4;
        #pragma unroll
        for (int mt = 0; mt < 4; ++mt)
            #pragma unroll
            for (int r = 0; r < 4; ++r) {
                int oc = (mt << 4) + (q << 2) + r;
                ob[(oc << 12) + pxb + l15] = acc[i][mt][r];
            }
    }
    // fused GN stat partials
    #pragma unroll
    for (int mt = 0; mt < 4; ++mt) {
        #pragma unroll
        for (int r = 0; r < 4; ++r) {
            float s = 0.f, s2 = 0.f;
            #pragma unroll
            for (int i = 0; i < 2; ++i) { float v = acc[i][mt][r]; s += v; s2 += v * v; }
            #pragma unroll
            for (int off = 1; off < 16; off <<= 1) {
                s  += __shfl_xor(s, off, 64);
                s2 += __shfl_xor(s2, off, 64);
            }
            if (l15 == 0) {
                int oc = (mt << 4) + (q << 2) + r;
                Ps[wave][oc] = s; Ps2[wave][oc] = s2;
            }
        }
    }
    __syncthreads();
    if (tid < 64) {
        float s  = Ps[0][tid] + Ps[1][tid] + Ps[2][tid] + Ps[3][tid];
        float s2 = Ps2[0][tid] + Ps2[1][tid] + Ps2[2][tid] + Ps2[3][tid];
        int idx = (((b << 5) + blockIdx.x) << 6) + tid;
        P1[idx] = s; P2[idx] = s2;
    }
}

// ---------------- K4: corr = s*t_global + depthwise7x7 -> bf16 NCHW (inline s-GN finalize) ----------------
__global__ __launch_bounds__(256) void k4_corr(
    const float* __restrict__ sraw, const float* __restrict__ P1, const float* __restrict__ P2,
    const float* __restrict__ gnw, const float* __restrict__ gnb,
    const float* __restrict__ t_global, const float* __restrict__ t_kernel,
    unsigned short* __restrict__ corr)
{
    int bc = blockIdx.x;
    int b = bc >> 6, c = bc & 63;
    int tid = threadIdx.x;
    __shared__ float t4[70 * 70];
    __shared__ float ker[49];
    __shared__ float fin4[4];
    __shared__ float sAB[2];
    if (tid < 32) {   // finalize this block's GN coefs from 32 tile-partials x 2 channels
        int ch = (c & ~1) + (tid >> 4), k = tid & 15;
        int base = ((b << 5) + k) << 6;
        float s  = P1[base + ch] + P1[base + (16 << 6) + ch];
        float s2 = P2[base + ch] + P2[base + (16 << 6) + ch];
        #pragma unroll
        for (int off = 1; off < 16; off <<= 1) {
            s += __shfl_xor(s, off, 16); s2 += __shfl_xor(s2, off, 16);
        }
        if (k == 0) { fin4[tid >> 4] = s; fin4[2 + (tid >> 4)] = s2; }
    }
    for (int i = tid; i < 4900; i += 256) t4[i] = 0.f;
    if (tid < 49) ker[tid] = t_kernel[bc * 49 + tid];
    __syncthreads();
    if (tid == 0) {
        float S = fin4[0] + fin4[1], S2 = fin4[2] + fin4[3];
        float mean = S * (1.f / 8192.f);
        float var  = S2 * (1.f / 8192.f) - mean * mean;
        float inv  = rsqrtf(var + EPS);
        float a = gnw[c] * inv;
        sAB[0] = a; sAB[1] = gnb[c] - mean * a;
    }
    __syncthreads();
    float a = sAB[0], bb = sAB[1], tg = t_global[bc];
    const float4* sb4 = (const float4*)(sraw + ((long)bc << 12));
    for (int i4 = tid; i4 < 1024; i4 += 256) {
        float4 v4 = sb4[i4];
        int y = i4 >> 4, xx = (i4 & 15) << 2;
        float* dst = &t4[(y + 3) * 70 + xx + 3];
        float v;
        v = a * v4.x + bb; dst[0] = v > 0.f ? v : 0.f;
        v = a * v4.y + bb; dst[1] = v > 0.f ? v : 0.f;
        v = a * v4.z + bb; dst[2] = v > 0.f ? v : 0.f;
        v = a * v4.w + bb; dst[3] = v > 0.f ? v : 0.f;
    }
    __syncthreads();
    int x = tid & 63, ys = (tid >> 6) << 4;
    float acc[16];
    #pragma unroll
    for (int j = 0; j < 16; ++j) acc[j] = 0.f;
    #pragma unroll
    for (int kx = 0; kx < 7; ++kx) {
        float col[22];
        #pragma unroll
        for (int j = 0; j < 22; ++j) col[j] = t4[(ys + j) * 70 + x + kx];
        #pragma unroll
        for (int ky = 0; ky < 7; ++ky) {
            float kv = ker[ky * 7 + kx];
            #pragma unroll
            for (int j = 0; j < 16; ++j) acc[j] += kv * col[j + ky];
        }
    }
    unsigned short* ob = corr + ((long)bc << 12);
    #pragma unroll
    for (int j = 0; j < 16; ++j) {
        float sval = t4[(ys + j + 3) * 70 + x + 3];
        ob[((ys + j) << 6) + x] = f2bf(acc[j] + sval * tg);
    }
}

// ---------------- K5: conv3x3 via bf16 MFMA, reads NCHW bf16 corr directly ----------------
// Staging does the NCHW->NHWC transpose into the xor-swizzled LDS tile (kills the k_t kernel).
__global__ __launch_bounds__(256) void k5_mfma(
    const unsigned short* __restrict__ corrB, const unsigned short* __restrict__ wpk,
    unsigned short* __restrict__ y, float* __restrict__ P1, float* __restrict__ P2)
{
    int b = blockIdx.y, py0 = blockIdx.x << 1;
    int tid = threadIdx.x;
    int wave = tid >> 6, lane = tid & 63, q = lane >> 4, l15 = lane & 15;
    __shared__ short tile[16896];   // [row 4][col 66][ic 64] bf16, xor-swizzled (33792 B)
    __shared__ float Ys[4][64], Ys2[4][64];

    {
        int row = tid >> 6, ic = tid & 63;   // wave = one tile row, lane = ic
        int py = py0 - 1 + row;
        int rbase = (row * 66) << 6;
        int icblk = ic >> 3, icl = ic & 7;
        if (py >= 0 && py < 64) {
            const uint4* src = (const uint4*)(corrB + (((long)(b << 6) + ic) << 12) + (py << 6));
            #pragma unroll
            for (int c8 = 0; c8 < 8; ++c8) {
                uint4 u = src[c8];
                const unsigned short* us = (const unsigned short*)&u;
                #pragma unroll
                for (int e = 0; e < 8; ++e) {
                    int col = (c8 << 3) + e + 1;
                    int sw = icblk ^ (col & 7);
                    tile[rbase + (col << 6) + (sw << 3) + icl] = us[e];
                }
            }
        } else {
            for (int col = 1; col <= 64; ++col) {
                int sw = icblk ^ (col & 7);
                tile[rbase + (col << 6) + (sw << 3) + icl] = 0;
            }
        }
        // halo cols 0 (px=-1) and 65 (px=64) are always out of image -> zero
        tile[rbase + (icblk << 3) + icl] = 0;
        tile[rbase + (65 << 6) + (((icblk ^ 1) << 3)) + icl] = 0;
    }
    __syncthreads();

    floatx4 acc[2][4];
    #pragma unroll
    for (int i = 0; i < 2; ++i)
        #pragma unroll
        for (int ot = 0; ot < 4; ++ot) acc[i][ot] = (floatx4){0.f, 0.f, 0.f, 0.f};

    int pt0 = wave << 1;
    int rowb[2], colb[2];
    #pragma unroll
    for (int i = 0; i < 2; ++i) {
        int p = ((pt0 + i) << 4) + l15;
        rowb[i] = p >> 6;
        colb[i] = p & 63;
    }
    #pragma unroll
    for (int c = 0; c < 18; ++c) {
        const int tap = c >> 1, ky = tap / 3, kx = tap % 3, h = c & 1;
        short8 bfr[4], afr[2];
        #pragma unroll
        for (int ot = 0; ot < 4; ++ot)
            bfr[ot] = *(const short8*)(wpk + ((c << 6) + (ot << 4) + l15) * 32 + (q << 3));
        #pragma unroll
        for (int i = 0; i < 2; ++i) {
            int row = rowb[i] + ky, col = colb[i] + kx;
            int sw = ((h << 2) + q) ^ (col & 7);
            afr[i] = *(const short8*)&tile[((row * 66 + col) << 6) + (sw << 3)];
        }
        #pragma unroll
        for (int i = 0; i < 2; ++i)
            #pragma unroll
            for (int ot = 0; ot < 4; ++ot)
                acc[i][ot] = __builtin_amdgcn_mfma_f32_16x16x32_bf16(afr[i], bfr[ot], acc[i][ot], 0, 0, 0);
    }
    #pragma unroll
    for (int i = 0; i < 2; ++i) {
        #pragma unroll
        for (int r = 0; r < 4; ++r) {
            int p = ((pt0 + i) << 4) + (q << 2) + r;
            int py = py0 + (p >> 6), pxc = p & 63;
            int base = ((b << 12) + (py << 6) + pxc) << 6;
            #pragma unroll
            for (int ot = 0; ot < 4; ++ot)
                y[base + (ot << 4) + l15] = f2bf(acc[i][ot][r]);
        }
    }
    // fused GN stat partials: lane holds oc = ot*16 + l15
    #pragma unroll
    for (int ot = 0; ot < 4; ++ot) {
        float s = 0.f, s2 = 0.f;
        #pragma unroll
        for (int i = 0; i < 2; ++i)
            #pragma unroll
            for (int r = 0; r < 4; ++r) { float v = acc[i][ot][r]; s += v; s2 += v * v; }
        s += __shfl_xor(s, 16, 64); s2 += __shfl_xor(s2, 16, 64);
        s += __shfl_xor(s, 32, 64); s2 += __shfl_xor(s2, 32, 64);
        if (lane < 16) { Ys[wave][(ot << 4) + lane] = s; Ys2[wave][(ot << 4) + lane] = s2; }
    }
    __syncthreads();
    if (tid < 64) {
        float s  = Ys[0][tid] + Ys[1][tid] + Ys[2][tid] + Ys[3][tid];
        float s2 = Ys2[0][tid] + Ys2[1][tid] + Ys2[2][tid] + Ys2[3][tid];
        int idx = (((b << 5) + blockIdx.x) << 6) + tid;
        P1[idx] = s; P2[idx] = s2;
    }
}

// ---------------- K6: epilogue on NHWC bf16 y (inline y-GN finalize) ----------------
__global__ __launch_bounds__(256) void k6_nhwc(
    const unsigned short* __restrict__ y, const float* __restrict__ P1, const float* __restrict__ P2,
    const float* __restrict__ gnw, const float* __restrict__ gnb,
    const float* __restrict__ w2, const float* __restrict__ b2, float* __restrict__ out)
{
    int b = blockIdx.y;
    int px0 = blockIdx.x << 7;
    int tid = threadIdx.x, wave = tid >> 6, lane = tid & 63;
    __shared__ float sA[64], sB[64];
    if (tid < 64) {
        int c = tid;
        float s = 0.f, s2 = 0.f;
        for (int t = 0; t < 32; ++t) {
            int idx = (((b << 5) + t) << 6) + c;
            s += P1[idx]; s2 += P2[idx];
        }
        float sp = __shfl_xor(s, 1, 64), s2p = __shfl_xor(s2, 1, 64);
        float S = s + sp, S2 = s2 + s2p;
        float mean = S * (1.f / 8192.f);
        float var  = S2 * (1.f / 8192.f) - mean * mean;
        float inv  = rsqrtf(var + EPS);
        float a = gnw[c] * inv;
        sA[c] = a; sB[c] = gnb[c] - mean * a;
    }
    __syncthreads();
    int ocp = lane & 31, ph = lane >> 5;
    int c0 = 2 * ocp;
    float a0 = sA[c0],     b0 = sB[c0],     w20 = w2[c0];
    float a1 = sA[c0 + 1], b1 = sB[c0 + 1], w21 = w2[c0 + 1];
    float bias = b2[0];
    const unsigned* yp = (const unsigned*)y;
    for (int i = 0; i < 16; ++i) {
        int px = px0 + (i << 3) + (wave << 1) + ph;
        unsigned u = yp[(((b << 12) + px) << 5) + ocp];
        float f0 = bf2f((unsigned short)(u & 0xFFFF));
        float f1 = bf2f((unsigned short)(u >> 16));
        float v0 = a0 * f0 + b0; v0 = v0 > 0.f ? v0 : 0.f;
        float v1 = a1 * f1 + b1; v1 = v1 > 0.f ? v1 : 0.f;
        float val = w20 * v0 + w21 * v1;
        #pragma unroll
        for (int m = 16; m >= 1; m >>= 1) val += __shfl_xor(val, m, 64);
        if (ocp == 0) out[(b << 12) + px] = val + bias;
    }
}

extern "C" void kernel_launch(void* const* d_in, const int* in_sizes, int n_in,
                              void* d_out, int out_size, void* d_ws, size_t ws_size,
                              hipStream_t stream)
{
    const float* tmpl   = (const float*)d_in[0];
    const float* search = (const float*)d_in[1];
    const float* w_t    = (const float*)d_in[2];
    const float* gn_t_w = (const float*)d_in[3];
    const float* gn_t_b = (const float*)d_in[4];
    const float* w_s    = (const float*)d_in[5];
    const float* gn_s_w = (const float*)d_in[6];
    const float* gn_s_b = (const float*)d_in[7];
    const float* w_p1   = (const float*)d_in[8];
    const float* gn_p_w = (const float*)d_in[9];
    const float* gn_p_b = (const float*)d_in[10];
    const float* w_p2   = (const float*)d_in[11];
    const float* b_p2   = (const float*)d_in[12];
    float* out = (float*)d_out;
    float* ws  = (float*)d_ws;

    float* TG   = ws;                    // 2048
    float* TK   = ws + 2048;             // 100352 -> ends 102400
    float* P1   = ws + 102400;           // 65536 (32b x 32 tiles x 64 oc) -> ends 167936
    float* P2   = ws + 167936;           // 65536 -> ends 233472
    unsigned short* WPK = (unsigned short*)(ws + 233472);   // 36864 bf16 -> ends 251904
    float* SRAW = ws + 262144;           // 8388608 floats (32 MB) -> ends 8650752
    unsigned short* CORRB = (unsigned short*)(ws + 8650752); // 4194304 bf16 (8 MB)
    // overlays (timeline-disjoint):
    unsigned short* WSB   = (unsigned short*)CORRB;          // k_pack writes, k2 reads; k4 overwrites
    unsigned short* YRAW  = (unsigned short*)SRAW;           // k5 writes after SRAW dead (k4 last reader)

    k_pack<<<208, 256, 0, stream>>>(w_s, WSB, w_p1, WPK);
    k1_template<<<256, 256, 0, stream>>>(tmpl, w_t, gn_t_w, gn_t_b, TG, TK);
    k2_mfma<<<dim3(32, 32), 256, 0, stream>>>(search, WSB, SRAW, P1, P2);
    k4_corr<<<2048, 256, 0, stream>>>(SRAW, P1, P2, gn_s_w, gn_s_b, TG, TK, CORRB);
    k5_mfma<<<dim3(32, 32), 256, 0, stream>>>(CORRB, WPK, YRAW, P1, P2);
    k6_nhwc<<<dim3(32, 32), 256, 0, stream>>>(YRAW, P1, P2, gn_p_w, gn_p_b, w_p2, b_p2, out);
}